// Round 5
// baseline (226.011 us; speedup 1.0000x reference)
//
#include <hip/hip_runtime.h>

#define SRATE 44100.0
#define L_CHUNK 64
#define SAMPLES_PER_CH 2097152
#define CHUNKS_PER_CH 32768
#define NCH 8
#define TOTAL_CHUNKS 262144
#define CPB 256                       // chunks per block
#define NBLK 1024                     // TOTAL_CHUNKS / CPB
#define BLK_PER_CH 128                // CHUNKS_PER_CH / CPB
#define NWIN 4
#define WIN 16
#define STRIDE 17                     // LDS row stride (floats)

#ifndef M_PI
#define M_PI 3.14159265358979323846
#endif

struct CoefD { double b0, b1, b2, a1, a2; };

__device__ void cascade_step_d(const CoefD* cf, double* s, double x) {
    double u = x;
    #pragma unroll
    for (int i = 0; i < 5; i++) {
        double y   = cf[i].b0 * u + s[2*i];
        double s1n = cf[i].b1 * u - cf[i].a1 * y + s[2*i+1];
        double s2n = cf[i].b2 * u - cf[i].a2 * y;
        s[2*i]   = s1n;
        s[2*i+1] = s2n;
        u = y;
    }
}

// K0: coefficients + fp32 matrix powers + flag clear.
// mats_f[0..799]    : Pd[d] = A^(64*2^d),    d=0..7
// mats_f[800..1499] : Qe[e] = A^(16384*2^e), e=0..6
__global__ __launch_bounds__(128) void k0_setup(const float* __restrict__ eqp,
                                                float* __restrict__ coef_f,
                                                float* __restrict__ mats_f,
                                                unsigned* __restrict__ flags) {
    __shared__ CoefD cf[5];
    __shared__ double M[100];
    int t = threadIdx.x;

    // clear publication flags (ws is poisoned 0xAA before every launch)
    for (int i = t; i < NBLK; i += 128) flags[i] = 0u;

    if (t == 0) {
        for (int i = 0; i < 5; i++) {
            double g  = (double)eqp[i*3 + 0];
            double fc = (double)eqp[i*3 + 1];
            double q  = (double)eqp[i*3 + 2];
            double A  = pow(10.0, g / 40.0);
            double w0 = 2.0 * M_PI * (fc / SRATE);
            double al = sin(w0) / (2.0 * q);
            double c  = cos(w0);
            double b0, b1, b2, a0, a1, a2;
            if (i == 0 || i == 4) {
                double sgn = (i == 4) ? 1.0 : -1.0;
                double sA = sqrt(A);
                b0 = A * ((A + 1.0) + sgn * (A - 1.0) * c + 2.0 * sA * al);
                b1 = -2.0 * sgn * A * ((A - 1.0) + sgn * (A + 1.0) * c);
                b2 = A * ((A + 1.0) + sgn * (A - 1.0) * c - 2.0 * sA * al);
                a0 = (A + 1.0) - sgn * (A - 1.0) * c + 2.0 * sA * al;
                a1 = 2.0 * sgn * ((A - 1.0) - sgn * (A + 1.0) * c);
                a2 = (A + 1.0) - sgn * (A - 1.0) * c - 2.0 * sA * al;
            } else {
                b0 = 1.0 + al * A; b1 = -2.0 * c; b2 = 1.0 - al * A;
                a0 = 1.0 + al / A; a1 = -2.0 * c; a2 = 1.0 - al / A;
            }
            cf[i].b0 = b0 / a0; cf[i].b1 = b1 / a0; cf[i].b2 = b2 / a0;
            cf[i].a1 = a1 / a0; cf[i].a2 = a2 / a0;
            coef_f[i*5 + 0] = (float)(b0 / a0);
            coef_f[i*5 + 1] = (float)(b1 / a0);
            coef_f[i*5 + 2] = (float)(b2 / a0);
            coef_f[i*5 + 3] = (float)(a1 / a0);
            coef_f[i*5 + 4] = (float)(a2 / a0);
        }
    }
    __syncthreads();

    if (t < 10) {
        double s[10];
        for (int k = 0; k < 10; k++) s[k] = (k == t) ? 1.0 : 0.0;
        cascade_step_d(cf, s, 0.0);
        for (int r = 0; r < 10; r++) M[r*10 + t] = s[r];
    }
    __syncthreads();

    for (int k = 1; k <= 20; k++) {
        double val = 0.0;
        if (t < 100) {
            int r = t / 10, c = t % 10;
            for (int j = 0; j < 10; j++) val += M[r*10 + j] * M[j*10 + c];
        }
        __syncthreads();
        if (t < 100) {
            M[t] = val;
            if (k >= 6 && k <= 13)  mats_f[(k-6)*100 + t]        = (float)val;
            if (k >= 14)            mats_f[800 + (k-14)*100 + t] = (float)val;
        }
        __syncthreads();
    }
}

__device__ __forceinline__ float cascade5(float u, float* s,
                                          const float* b0, const float* b1,
                                          const float* b2, const float* a1,
                                          const float* a2) {
    #pragma unroll
    for (int st = 0; st < 5; st++) {
        float y  = fmaf(b0[st], u, s[2*st]);
        float t1 = fmaf(b1[st], u, s[2*st+1]);
        s[2*st+1] = fmaf(-a2[st], y, b2[st] * u);
        s[2*st]   = fmaf(-a1[st], y, t1);
        u = y;
    }
    return u;
}

// Single fused kernel, regular launch. Cross-block dependency resolved with
// per-block published aggregates + flags (wait only on LOWER block IDs ->
// deadlock-free under in-order workgroup dispatch, like rocPRIM scan).
__global__ __launch_bounds__(256, 4) void k_main(const float* __restrict__ x,
                                                 const float* __restrict__ coef,
                                                 const float* __restrict__ mats_f,
                                                 float* __restrict__ abuf,
                                                 unsigned* __restrict__ flags,
                                                 float* __restrict__ out) {
    __shared__ float smem[CPB * STRIDE];   // scan buf / agg buf / out staging
    __shared__ float Mds[1500];
    const int t = threadIdx.x, b = blockIdx.x;
    const int ch     = b >> 7;
    const int ch_blk = b & (BLK_PER_CH - 1);

    for (int i = t; i < 1500; i += 256) Mds[i] = mats_f[i];

    float cb0[5], cb1[5], cb2[5], ca1[5], ca2[5];
    #pragma unroll
    for (int i = 0; i < 5; i++) {
        cb0[i] = coef[i*5+0]; cb1[i] = coef[i*5+1]; cb2[i] = coef[i*5+2];
        ca1[i] = coef[i*5+3]; ca2[i] = coef[i*5+4];
    }

    // ---- phase 1: zero-state cascade over this thread's 64-sample chunk ----
    const float4* x4 = (const float4*)x;
    const size_t tb4 = (size_t)b * 4096 + (size_t)t * 16;
    float s[10];
    #pragma unroll
    for (int k = 0; k < 10; k++) s[k] = 0.0f;
    #pragma unroll
    for (int k = 0; k < 16; k++) {
        float4 xv = x4[tb4 + k];
        cascade5(xv.x, s, cb0, cb1, cb2, ca1, ca2);
        cascade5(xv.y, s, cb0, cb1, cb2, ca1, ca2);
        cascade5(xv.z, s, cb0, cb1, cb2, ca1, ca2);
        cascade5(xv.w, s, cb0, cb1, cb2, ca1, ca2);
    }

    // ---- in-block Kogge-Stone scan over 256 chunk states ----
    __syncthreads();   // Mds ready
    #pragma unroll
    for (int r = 0; r < 10; r++) smem[t*11 + r] = s[r];
    __syncthreads();

    for (int d = 0; d < 8; d++) {
        float nv[10];
        bool act = (t >= (1 << d));
        if (act) {
            int src = t - (1 << d);
            #pragma unroll
            for (int r = 0; r < 10; r++) {
                float acc = s[r];
                #pragma unroll
                for (int k = 0; k < 10; k++)
                    acc = fmaf(Mds[d*100 + r*10 + k], smem[src*11 + k], acc);
                nv[r] = acc;
            }
        }
        __syncthreads();
        if (act) {
            #pragma unroll
            for (int r = 0; r < 10; r++) { s[r] = nv[r]; smem[t*11 + r] = nv[r]; }
        }
        __syncthreads();
    }

    // exclusive local prefix -> registers
    float p[10];
    #pragma unroll
    for (int r = 0; r < 10; r++) p[r] = (t > 0) ? smem[(t-1)*11 + r] : 0.0f;

    // publish block aggregate (inclusive total = s of t==255)
    if (t == 255) {
        #pragma unroll
        for (int r = 0; r < 10; r++)
            __hip_atomic_store(&abuf[b*10 + r], s[r],
                               __ATOMIC_RELAXED, __HIP_MEMORY_SCOPE_AGENT);
        __hip_atomic_store(&flags[b], 1u,
                           __ATOMIC_RELEASE, __HIP_MEMORY_SCOPE_AGENT);
    }

    // ---- wait for this channel's predecessor aggregates (lower IDs only) ----
    if (t < ch_blk) {
        const unsigned* fp = &flags[ch * BLK_PER_CH + t];
        while (__hip_atomic_load(fp, __ATOMIC_ACQUIRE,
                                 __HIP_MEMORY_SCOPE_AGENT) == 0u) {
            __builtin_amdgcn_s_sleep(8);
        }
    }
    __syncthreads();   // all threads done with scan-phase smem too

    // ---- phase 2: KS scan over ch_blk predecessor aggregates ----
    float v2[10];
    if (t < ch_blk) {
        const float* ap = &abuf[(ch * BLK_PER_CH + t) * 10];
        #pragma unroll
        for (int r = 0; r < 10; r++) {
            v2[r] = __hip_atomic_load(&ap[r], __ATOMIC_RELAXED,
                                      __HIP_MEMORY_SCOPE_AGENT);
            smem[t*11 + r] = v2[r];
        }
    }
    __syncthreads();

    for (int e = 0; e < 7; e++) {
        if ((1 << e) >= ch_blk) break;      // block-uniform
        float nv[10];
        bool act = (t < ch_blk) && (t >= (1 << e));
        if (act) {
            int src = t - (1 << e);
            #pragma unroll
            for (int r = 0; r < 10; r++) {
                float acc = v2[r];
                #pragma unroll
                for (int k = 0; k < 10; k++)
                    acc = fmaf(Mds[800 + e*100 + r*10 + k], smem[src*11 + k], acc);
                nv[r] = acc;
            }
        }
        __syncthreads();
        if (act) {
            #pragma unroll
            for (int r = 0; r < 10; r++) { v2[r] = nv[r]; smem[t*11 + r] = nv[r]; }
        }
        __syncthreads();
    }

    // channel prefix entering this block
    float w[10];
    #pragma unroll
    for (int r = 0; r < 10; r++)
        w[r] = (ch_blk > 0) ? smem[(ch_blk-1)*11 + r] : 0.0f;
    __syncthreads();   // smem free for out-staging

    // re-issue x loads early (L2/L3-warm) to overlap the decomp math
    float4 xr[16];
    #pragma unroll
    for (int k = 0; k < 16; k++) xr[k] = x4[tb4 + k];

    // ---- phase 3 init: s = p + A^(64*t) * w ----
    #pragma unroll
    for (int d = 0; d < 8; d++) {
        float wv[10];
        #pragma unroll
        for (int r = 0; r < 10; r++) {
            float acc = 0.0f;
            #pragma unroll
            for (int k = 0; k < 10; k++)
                acc = fmaf(Mds[d*100 + r*10 + k], w[k], acc);
            wv[r] = acc;
        }
        bool bit = (t >> d) & 1;
        #pragma unroll
        for (int r = 0; r < 10; r++) w[r] = bit ? wv[r] : w[r];
    }
    #pragma unroll
    for (int r = 0; r < 10; r++) s[r] = p[r] + w[r];

    // ---- phase 3: rerun cascade, coalesced stores via LDS transpose ----
    float4* o4 = (float4*)out;
    const size_t base4 = (size_t)b * 4096;
    const int cbi = t >> 2, q = t & 3;

    #pragma unroll
    for (int wnd = 0; wnd < NWIN; wnd++) {
        float* orow = smem + t * STRIDE;
        #pragma unroll
        for (int k = 0; k < 4; k++) {
            const float4 xv = xr[wnd*4 + k];
            orow[k*4+0] = cascade5(xv.x, s, cb0, cb1, cb2, ca1, ca2);
            orow[k*4+1] = cascade5(xv.y, s, cb0, cb1, cb2, ca1, ca2);
            orow[k*4+2] = cascade5(xv.z, s, cb0, cb1, cb2, ca1, ca2);
            orow[k*4+3] = cascade5(xv.w, s, cb0, cb1, cb2, ca1, ca2);
        }
        __syncthreads();

        #pragma unroll
        for (int k = 0; k < 4; k++) {
            int o = (cbi + 64*k) * STRIDE + q*4;
            float4 ov = make_float4(smem[o+0], smem[o+1], smem[o+2], smem[o+3]);
            o4[base4 + (size_t)(cbi + 64*k) * 16 + (size_t)wnd*4 + q] = ov;
        }
        __syncthreads();
    }
}

extern "C" void kernel_launch(void* const* d_in, const int* in_sizes, int n_in,
                              void* d_out, int out_size, void* d_ws, size_t ws_size,
                              hipStream_t stream) {
    const float* x   = (const float*)d_in[0];
    const float* eqp = (const float*)d_in[1];
    float* out = (float*)d_out;
    char* ws = (char*)d_ws;

    float*    coef_f = (float*)ws;                 // 25 floats
    float*    mats_f = (float*)(ws + 256);         // 1500 floats
    float*    abuf   = (float*)(ws + 8192);        // 1024*10 floats
    unsigned* flags  = (unsigned*)(ws + 65536);    // 1024 uints

    hipLaunchKernelGGL(k0_setup, dim3(1), dim3(128), 0, stream,
                       eqp, coef_f, mats_f, flags);
    hipLaunchKernelGGL(k_main, dim3(NBLK), dim3(256), 0, stream,
                       x, coef_f, mats_f, abuf, flags, out);
}

// Round 6
// 196.081 us; speedup vs baseline: 1.1526x; 1.1526x over previous
//
#include <hip/hip_runtime.h>

#define SRATE 44100.0
#define L_CHUNK 32
#define SAMPLES_PER_CH 2097152
#define CHUNKS_PER_CH 65536           // SAMPLES_PER_CH / L_CHUNK
#define NCH 8
#define TOTAL_CHUNKS 524288
#define CPB 256                       // chunks per block (= threads per block)
#define NBLK 2048                     // TOTAL_CHUNKS / CPB
#define BLK_PER_CH 256                // CHUNKS_PER_CH / CPB
#define SROW 34                       // LDS row stride in floats (136 B, 8B-aligned)

#ifndef M_PI
#define M_PI 3.14159265358979323846
#endif

struct CoefD { double b0, b1, b2, a1, a2; };

__device__ void cascade_step_d(const CoefD* cf, double* s, double x) {
    double u = x;
    #pragma unroll
    for (int i = 0; i < 5; i++) {
        double y   = cf[i].b0 * u + s[2*i];
        double s1n = cf[i].b1 * u - cf[i].a1 * y + s[2*i+1];
        double s2n = cf[i].b2 * u - cf[i].a2 * y;
        s[2*i]   = s1n;
        s[2*i+1] = s2n;
        u = y;
    }
}

// K0: coefficients + fp32 matrix powers.
// mats_f[0..799]     : Pd[d] = A^(32*2^d),   d=0..7  (in-block scan + k3 decomp)
// mats_f[800..1599]  : Qe[e] = A^(8192*2^e), e=0..7  (cross-block scan, folded in k3)
__global__ __launch_bounds__(128) void k0_setup(const float* __restrict__ eqp,
                                                float* __restrict__ coef_f,
                                                float* __restrict__ mats_f) {
    __shared__ CoefD cf[5];
    __shared__ double M[100];
    int t = threadIdx.x;

    if (t < 5) {
        int i = t;
        double g  = (double)eqp[i*3 + 0];
        double fc = (double)eqp[i*3 + 1];
        double q  = (double)eqp[i*3 + 2];
        double A  = pow(10.0, g / 40.0);
        double w0 = 2.0 * M_PI * (fc / SRATE);
        double al = sin(w0) / (2.0 * q);
        double c  = cos(w0);
        double b0, b1, b2, a0, a1, a2;
        if (i == 0 || i == 4) {
            double sgn = (i == 4) ? 1.0 : -1.0;
            double sA = sqrt(A);
            b0 = A * ((A + 1.0) + sgn * (A - 1.0) * c + 2.0 * sA * al);
            b1 = -2.0 * sgn * A * ((A - 1.0) + sgn * (A + 1.0) * c);
            b2 = A * ((A + 1.0) + sgn * (A - 1.0) * c - 2.0 * sA * al);
            a0 = (A + 1.0) - sgn * (A - 1.0) * c + 2.0 * sA * al;
            a1 = 2.0 * sgn * ((A - 1.0) - sgn * (A + 1.0) * c);
            a2 = (A + 1.0) - sgn * (A - 1.0) * c - 2.0 * sA * al;
        } else {
            b0 = 1.0 + al * A; b1 = -2.0 * c; b2 = 1.0 - al * A;
            a0 = 1.0 + al / A; a1 = -2.0 * c; a2 = 1.0 - al / A;
        }
        cf[i].b0 = b0 / a0; cf[i].b1 = b1 / a0; cf[i].b2 = b2 / a0;
        cf[i].a1 = a1 / a0; cf[i].a2 = a2 / a0;
        coef_f[i*5 + 0] = (float)(b0 / a0);
        coef_f[i*5 + 1] = (float)(b1 / a0);
        coef_f[i*5 + 2] = (float)(b2 / a0);
        coef_f[i*5 + 3] = (float)(a1 / a0);
        coef_f[i*5 + 4] = (float)(a2 / a0);
    }
    __syncthreads();

    // A: column j = step(e_j, x=0)
    if (t < 10) {
        double s[10];
        for (int k = 0; k < 10; k++) s[k] = (k == t) ? 1.0 : 0.0;
        cascade_step_d(cf, s, 0.0);
        for (int r = 0; r < 10; r++) M[r*10 + t] = s[r];
    }
    __syncthreads();

    // repeated squaring: after k squarings, M = A^(2^k)
    for (int k = 1; k <= 20; k++) {
        double val = 0.0;
        if (t < 100) {
            int r = t / 10, c = t % 10;
            for (int j = 0; j < 10; j++) val += M[r*10 + j] * M[j*10 + c];
        }
        __syncthreads();
        if (t < 100) {
            M[t] = val;
            if (k >= 5 && k <= 12)  mats_f[(k-5)*100 + t]        = (float)val;  // Pd
            if (k >= 13)            mats_f[800 + (k-13)*100 + t] = (float)val;  // Qe
        }
        __syncthreads();
    }
}

__device__ __forceinline__ float cascade5(float u, float* s,
                                          const float* b0, const float* b1,
                                          const float* b2, const float* a1,
                                          const float* a2) {
    #pragma unroll
    for (int st = 0; st < 5; st++) {
        float y  = fmaf(b0[st], u, s[2*st]);
        float t1 = fmaf(b1[st], u, s[2*st+1]);
        s[2*st+1] = fmaf(-a2[st], y, b2[st] * u);
        s[2*st]   = fmaf(-a1[st], y, t1);
        u = y;
    }
    return u;
}

// K1: contiguous-burst load -> LDS transpose -> zero-state cascade ->
// in-block KS scan -> exclusive prefixes (ibuf) + block aggregate (abuf).
__global__ __launch_bounds__(256, 4) void k1_partial(const float* __restrict__ x,
                                                     const float* __restrict__ coef,
                                                     const float* __restrict__ mats_f,
                                                     float* __restrict__ ibuf,
                                                     float* __restrict__ abuf) {
    __shared__ float buf[CPB * SROW];     // 34816 B; x-tile, then scan buf
    __shared__ float Mds[800];            // Pd
    const int t = threadIdx.x, b = blockIdx.x;

    // 8 fully-contiguous 1KB wave-bursts: block input = 32 KB contiguous
    const float4* x4 = (const float4*)x;
    const size_t base4 = (size_t)b * 2048;
    float4 xr[8];
    #pragma unroll
    for (int p = 0; p < 8; p++) xr[p] = x4[base4 + p*256 + t];

    for (int i = t; i < 800; i += 256) Mds[i] = mats_f[i];

    float cb0[5], cb1[5], cb2[5], ca1[5], ca2[5];
    #pragma unroll
    for (int i = 0; i < 5; i++) {
        cb0[i] = coef[i*5+0]; cb1[i] = coef[i*5+1]; cb2[i] = coef[i*5+2];
        ca1[i] = coef[i*5+3]; ca2[i] = coef[i*5+4];
    }

    // transpose on LDS write: word j = 1024p + 4t(+c); row=j>>5=32p+(t>>3)
    const int rb = t >> 3, cm = 4 * (t & 7);
    #pragma unroll
    for (int p = 0; p < 8; p++) {
        int a = (32*p + rb) * SROW + cm;
        *(float2*)&buf[a]     = make_float2(xr[p].x, xr[p].y);
        *(float2*)&buf[a + 2] = make_float2(xr[p].z, xr[p].w);
    }
    __syncthreads();

    // zero-state cascade over this thread's 32-sample chunk (row t)
    float s[10];
    #pragma unroll
    for (int k = 0; k < 10; k++) s[k] = 0.0f;
    const float* myrow = buf + t * SROW;
    #pragma unroll
    for (int i = 0; i < L_CHUNK; i++)
        cascade5(myrow[i], s, cb0, cb1, cb2, ca1, ca2);
    __syncthreads();   // buf reusable as scan buffer

    #pragma unroll
    for (int r = 0; r < 10; r++) buf[t*11 + r] = s[r];
    __syncthreads();

    for (int d = 0; d < 8; d++) {
        float nv[10];
        bool act = (t >= (1 << d));
        if (act) {
            int src = t - (1 << d);
            #pragma unroll
            for (int r = 0; r < 10; r++) {
                float acc = s[r];
                #pragma unroll
                for (int k = 0; k < 10; k++)
                    acc = fmaf(Mds[d*100 + r*10 + k], buf[src*11 + k], acc);
                nv[r] = acc;
            }
        }
        __syncthreads();
        if (act) {
            #pragma unroll
            for (int r = 0; r < 10; r++) { s[r] = nv[r]; buf[t*11 + r] = nv[r]; }
        }
        __syncthreads();
    }

    #pragma unroll
    for (int r = 0; r < 10; r++)
        ibuf[(size_t)b * 2560 + r * 256 + t] = (t > 0) ? buf[(t-1)*11 + r] : 0.0f;
    if (t == 255) {
        #pragma unroll
        for (int r = 0; r < 10; r++) abuf[b*10 + r] = s[r];
    }
}

// K3: folded cross-block scan (redundant per block) + init + final cascade
// with contiguous-burst IO through the same LDS transpose (in-place).
__global__ __launch_bounds__(256, 4) void k3_final(const float* __restrict__ x,
                                                   const float* __restrict__ coef,
                                                   const float* __restrict__ mats_f,
                                                   const float* __restrict__ ibuf,
                                                   const float* __restrict__ abuf,
                                                   float* __restrict__ out) {
    __shared__ float buf[CPB * SROW];     // scan buf, then x/y tile (in-place)
    const int t = threadIdx.x, b = blockIdx.x;
    const int ch     = b >> 8;            // b / BLK_PER_CH
    const int ch_blk = b & (BLK_PER_CH - 1);

    // issue x loads first; they fly during the scan
    const float4* x4 = (const float4*)x;
    const size_t base4 = (size_t)b * 2048;
    float4 xr[8];
    #pragma unroll
    for (int p = 0; p < 8; p++) xr[p] = x4[base4 + p*256 + t];

    float cb0[5], cb1[5], cb2[5], ca1[5], ca2[5];
    #pragma unroll
    for (int i = 0; i < 5; i++) {
        cb0[i] = coef[i*5+0]; cb1[i] = coef[i*5+1]; cb2[i] = coef[i*5+2];
        ca1[i] = coef[i*5+3]; ca2[i] = coef[i*5+4];
    }

    // ---- cross-block KS scan over my channel's 256 aggregates ----
    float v[10];
    {
        const float* ap = &abuf[((size_t)ch * BLK_PER_CH + t) * 10];
        #pragma unroll
        for (int r = 0; r < 10; r++) { v[r] = ap[r]; buf[t*11 + r] = v[r]; }
    }
    __syncthreads();

    const float* Qg = mats_f + 800;
    for (int e = 0; e < 8; e++) {
        float nv[10];
        bool act = (t >= (1 << e));
        if (act) {
            int src = t - (1 << e);
            #pragma unroll
            for (int r = 0; r < 10; r++) {
                float acc = v[r];
                #pragma unroll
                for (int k = 0; k < 10; k++)
                    acc = fmaf(Qg[e*100 + r*10 + k], buf[src*11 + k], acc);
                nv[r] = acc;
            }
        }
        __syncthreads();
        if (act) {
            #pragma unroll
            for (int r = 0; r < 10; r++) { v[r] = nv[r]; buf[t*11 + r] = nv[r]; }
        }
        __syncthreads();
    }

    // channel prefix entering this block (broadcast)
    float w[10];
    #pragma unroll
    for (int r = 0; r < 10; r++)
        w[r] = (ch_blk > 0) ? buf[(ch_blk-1)*11 + r] : 0.0f;
    __syncthreads();   // buf free for the x tile

    // stage x into LDS (transposed), in-place tile
    const int rb = t >> 3, cm = 4 * (t & 7);
    #pragma unroll
    for (int p = 0; p < 8; p++) {
        int a = (32*p + rb) * SROW + cm;
        *(float2*)&buf[a]     = make_float2(xr[p].x, xr[p].y);
        *(float2*)&buf[a + 2] = make_float2(xr[p].z, xr[p].w);
    }

    // init: s = local_prefix + A^(32*t) * w   (Pd read uniform from L2)
    float s[10];
    #pragma unroll
    for (int r = 0; r < 10; r++)
        s[r] = ibuf[(size_t)b * 2560 + r * 256 + t];
    #pragma unroll
    for (int d = 0; d < 8; d++) {
        float wv[10];
        #pragma unroll
        for (int r = 0; r < 10; r++) {
            float acc = 0.0f;
            #pragma unroll
            for (int k = 0; k < 10; k++)
                acc = fmaf(mats_f[d*100 + r*10 + k], w[k], acc);
            wv[r] = acc;
        }
        bool bit = (t >> d) & 1;
        #pragma unroll
        for (int r = 0; r < 10; r++) w[r] = bit ? wv[r] : w[r];
    }
    #pragma unroll
    for (int r = 0; r < 10; r++) s[r] += w[r];
    __syncthreads();   // tile staged

    // final cascade, in-place overwrite of row t
    float* myrow = buf + t * SROW;
    #pragma unroll
    for (int i = 0; i < L_CHUNK; i++)
        myrow[i] = cascade5(myrow[i], s, cb0, cb1, cb2, ca1, ca2);
    __syncthreads();

    // contiguous-burst store (mirror of the load)
    float4* o4 = (float4*)out;
    #pragma unroll
    for (int p = 0; p < 8; p++) {
        int a = (32*p + rb) * SROW + cm;
        float2 lo = *(const float2*)&buf[a];
        float2 hi = *(const float2*)&buf[a + 2];
        o4[base4 + p*256 + t] = make_float4(lo.x, lo.y, hi.x, hi.y);
    }
}

extern "C" void kernel_launch(void* const* d_in, const int* in_sizes, int n_in,
                              void* d_out, int out_size, void* d_ws, size_t ws_size,
                              hipStream_t stream) {
    const float* x   = (const float*)d_in[0];
    const float* eqp = (const float*)d_in[1];
    float* out = (float*)d_out;
    char* ws = (char*)d_ws;

    float* coef_f = (float*)ws;                  // 25 floats
    float* mats_f = (float*)(ws + 256);          // 1600 floats
    float* abuf   = (float*)(ws + 8192);         // 2048*10 floats = 81920 B
    float* ibuf   = (float*)(ws + 131072);       // 524288*10*4 = 20.97 MB

    hipLaunchKernelGGL(k0_setup, dim3(1), dim3(128), 0, stream, eqp, coef_f, mats_f);
    hipLaunchKernelGGL(k1_partial, dim3(NBLK), dim3(256), 0, stream,
                       x, coef_f, mats_f, ibuf, abuf);
    hipLaunchKernelGGL(k3_final, dim3(NBLK), dim3(256), 0, stream,
                       x, coef_f, mats_f, ibuf, abuf, out);
}